// Round 20
// baseline (171.770 us; speedup 1.0000x reference)
//
#include <hip/hip_runtime.h>
#include <hip/hip_bf16.h>

typedef __bf16 bf16;
typedef __bf16 bf16x8 __attribute__((ext_vector_type(8)));
typedef __bf16 bf16x4v __attribute__((ext_vector_type(4)));
typedef float f32x4 __attribute__((ext_vector_type(4)));
typedef float f32x16 __attribute__((ext_vector_type(16)));
typedef float float4v __attribute__((ext_vector_type(4)));
typedef unsigned int uint32x4 __attribute__((ext_vector_type(4)));

#define MFMA16(a, b, c) __builtin_amdgcn_mfma_f32_16x16x32_bf16(a, b, c, 0, 0, 0)
#define MFMA32(a, b, c) __builtin_amdgcn_mfma_f32_32x32x16_bf16(a, b, c, 0, 0, 0)

// q pre-scale: 1/sqrt(64) * log2(e)  (softmax runs in exp2 domain)
#define SCALE_Q 0.1803368801111f

__device__ __forceinline__ void async_load16(const bf16* g, bf16* l) {
    __builtin_amdgcn_global_load_lds(
        (const __attribute__((address_space(1))) void*)g,
        (__attribute__((address_space(3))) void*)l,
        16, 0, 0);
}

__device__ __forceinline__ unsigned int pack2bf(float a, float b) {
    bf16 x = (bf16)a, y = (bf16)b;
    unsigned short ux = __builtin_bit_cast(unsigned short, x);
    unsigned short uy = __builtin_bit_cast(unsigned short, y);
    return (unsigned int)ux | ((unsigned int)uy << 16);
}

// =================== fragment-packed layout ===================
// Element (row t, k) of a [T][K] bf16 matrix (K=1024) lives at:
//   line = (t>>4)*32 + (k>>5);  lane = (t&15) + 16*((k>>3)&3);  j = k&7
//   idx  = line*512 + lane*8 + j
// One MFMA A/B fragment (16 rows x 32 k) = one 1KB line = base + lane*16B.

// ---------------- k_pre: LDS-tiled packer (coalesced load + store) ----------------
__global__ __launch_bounds__(256) void k_pre(
    const float* __restrict__ x, const float* __restrict__ W_attn,
    const float* __restrict__ W_proj,
    bf16* __restrict__ xpk, float* __restrict__ out_mem,
    bf16* __restrict__ Wapk, bf16* __restrict__ Wppk) {
    __shared__ float tile[64][65];
    int bid = blockIdx.x, tid = threadIdx.x;

    if (bid < 2048) {
        int bt = bid >> 4, bk = bid & 15;
        int t0 = bt * 64, k0 = bk * 64;
#pragma unroll
        for (int i = 0; i < 4; ++i) {
            int idx = tid + 256 * i;
            int r = idx >> 4, c4 = (idx & 15) * 4;
            float4v v = *(const float4v*)(x + (size_t)(t0 + r) * 1024 + k0 + c4);
            *(float4v*)&tile[r][c4] = v;
            int tb = (t0 + r) & 2047;
            if (tb >= 1536) {
                int b = (t0 + r) >> 11;
                *(float4v*)(out_mem + ((size_t)(b * 512 + (tb - 1536))) * 1024 + k0 + c4) = v;
            }
        }
        __syncthreads();
#pragma unroll
        for (int i = 0; i < 2; ++i) {
            int idx = tid + 256 * i;
            int lineL = idx >> 6, lane = idx & 63;
            int slab_l = lineL >> 1, kc_l = lineL & 1;
            int tl = slab_l * 16 + (lane & 15);
            int kl = kc_l * 32 + (lane >> 4) * 8;
            bf16x8 o;
#pragma unroll
            for (int j = 0; j < 8; ++j)
                o[j] = (bf16)tile[tl][kl + j];
            size_t line_g = (size_t)(bt * 4 + slab_l) * 32 + (bk * 2 + kc_l);
            *(bf16x8*)(xpk + line_g * 512 + lane * 8) = o;
        }
    } else {
        const float* W;  bf16* WT;  int C, kt, nt;
        if (bid < 2816) {
            int b2 = bid - 2048;
            W = W_attn; WT = Wapk; C = 3072; kt = b2 & 15; nt = b2 >> 4;
        } else {
            int b3 = bid - 2816;
            W = W_proj; WT = Wppk; C = 1024; kt = b3 & 15; nt = b3 >> 4;
        }
        int k0 = kt * 64, n0 = nt * 64;
#pragma unroll
        for (int i = 0; i < 4; ++i) {
            int idx = tid + 256 * i;
            int r = idx >> 4, c4 = (idx & 15) * 4;
            *(float4v*)&tile[r][c4] = *(const float4v*)(W + (size_t)(k0 + r) * C + n0 + c4);
        }
        __syncthreads();
#pragma unroll
        for (int i = 0; i < 2; ++i) {
            int idx = tid + 256 * i;
            int lineL = idx >> 6, lane = idx & 63;
            int slab_l = lineL >> 1, kc_l = lineL & 1;
            int nl = slab_l * 16 + (lane & 15);
            int kl = kc_l * 32 + (lane >> 4) * 8;
            bf16x8 o;
#pragma unroll
            for (int j = 0; j < 8; ++j)
                o[j] = (bf16)tile[kl + j][nl];
            size_t line_g = (size_t)(nt * 4 + slab_l) * 32 + (kt * 2 + kc_l);
            *(bf16x8*)(WT + line_g * 512 + lane * 8) = o;
        }
    }
}

// ============ LDS-free GEMM body: per-wave 128x64 (8x4 frags) ============
#define GEMM_NOLDS_BODY84                                                                \
    const bf16* Abase = Apk + (size_t)(((row0 >> 4) + wr * 8) * 32) * 512 + lane * 8;    \
    const bf16* Bbase = Bpk + (size_t)(((col0 >> 4) + wc * 4) * 32) * 512 + lane * 8;    \
    f32x4 acc[8][4] = {};                                                                \
    bf16x8 a0[8], b0[4], a1[8], b1[4];                                                   \
    _Pragma("unroll")                                                                    \
    for (int m = 0; m < 8; ++m) a0[m] = *(const bf16x8*)(Abase + m * 16384);             \
    _Pragma("unroll")                                                                    \
    for (int n = 0; n < 4; ++n) b0[n] = *(const bf16x8*)(Bbase + n * 16384);             \
    for (int t = 0; t < 16; ++t) {                                                       \
        int o1 = (2 * t + 1) * 512;                                                      \
        _Pragma("unroll")                                                                \
        for (int m = 0; m < 8; ++m) a1[m] = *(const bf16x8*)(Abase + m * 16384 + o1);    \
        _Pragma("unroll")                                                                \
        for (int n = 0; n < 4; ++n) b1[n] = *(const bf16x8*)(Bbase + n * 16384 + o1);    \
        __builtin_amdgcn_s_setprio(1);                                                   \
        _Pragma("unroll")                                                                \
        for (int m = 0; m < 8; ++m)                                                      \
            _Pragma("unroll")                                                            \
            for (int n = 0; n < 4; ++n)                                                  \
                acc[m][n] = MFMA16(a0[m], b0[n], acc[m][n]);                             \
        __builtin_amdgcn_s_setprio(0);                                                   \
        if (t < 15) {                                                                    \
            int o2 = (2 * t + 2) * 512;                                                  \
            _Pragma("unroll")                                                            \
            for (int m = 0; m < 8; ++m) a0[m] = *(const bf16x8*)(Abase + m * 16384 + o2);\
            _Pragma("unroll")                                                            \
            for (int n = 0; n < 4; ++n) b0[n] = *(const bf16x8*)(Bbase + n * 16384 + o2);\
        }                                                                                \
        __builtin_amdgcn_s_setprio(1);                                                   \
        _Pragma("unroll")                                                                \
        for (int m = 0; m < 8; ++m)                                                      \
            _Pragma("unroll")                                                            \
            for (int n = 0; n < 4; ++n)                                                  \
                acc[m][n] = MFMA16(a1[m], b1[n], acc[m][n]);                             \
        __builtin_amdgcn_s_setprio(0);                                                   \
    }

// ---------------- QKV GEMM: 512 thr, 256x256 block (8 waves = 2M x 4N) ----------------
// Unique operand traffic drops to 128 B/MFMA: at 2 blocks/CU the L1 delivery
// requirement falls below its ~128 B/cy rate -> MFMA becomes the binding pipe.
// Grid 384 = 8 * 48, col-outer/row-inner XCD relabel (bijective).
__global__ __launch_bounds__(512, 2) void k_gemm_qkv(
    const bf16* __restrict__ Apk, const bf16* __restrict__ Bpk,
    const float* __restrict__ bias,
    bf16* __restrict__ qo, bf16* __restrict__ ko, bf16* __restrict__ vo) {
    int orig = blockIdx.x;
    int xcd = orig & 7, j = orig >> 3;           // j in [0,48)
    int col0 = (j >> 2) * 256;                   // 12 col panels, outer
    int row0 = (xcd * 4 + (j & 3)) * 256;        // 32 row panels, 4/XCD, inner
    int lane = threadIdx.x & 63, w = threadIdx.x >> 6;   // w in 0..7
    int wr = w >> 2, wc = w & 3;
    int lrow = lane & 15, lks = lane >> 4;

    GEMM_NOLDS_BODY84

    int trowb = row0 + wr * 128 + lks * 4;
    int tcolb = col0 + wc * 64 + lrow;
#pragma unroll
    for (int mf = 0; mf < 8; ++mf)
#pragma unroll
        for (int nf = 0; nf < 4; ++nf) {
            int cg = tcolb + nf * 16;
            float bi = bias[cg];
#pragma unroll
            for (int j2 = 0; j2 < 4; ++j2) {
                int rg = trowb + mf * 16 + j2;
                float val = acc[mf][nf][j2] + bi;
                int b = rg >> 11, tt = rg & 2047;
                if (cg < 1024) {
                    int h = cg >> 6, d = cg & 63;
                    size_t base = (size_t)(b * 16 + h) * 131072;
                    size_t idx = base + (size_t)((((tt >> 5) * 4 + (d >> 4)) * 64 + ((d >> 3) & 1) * 32 + (tt & 31)) * 8 + (d & 7));
                    qo[idx] = (bf16)(val * SCALE_Q);
                } else if (cg < 2048) {
                    int c2 = cg - 1024;
                    int h = c2 >> 6, d = c2 & 63;
                    size_t base = (size_t)(b * 16 + h) * 131072;
                    size_t idx = base + (size_t)((((tt >> 5) * 4 + (d >> 4)) * 64 + ((d >> 3) & 1) * 32 + (tt & 31)) * 8 + (d & 7));
                    ko[idx] = (bf16)val;
                } else {
                    int c2 = cg - 2048;
                    int h = c2 >> 6, d = c2 & 63;
                    size_t base = (size_t)(b * 16 + h) * 131072;
                    size_t idx = base + (size_t)(((((tt >> 6) * 4 + ((tt >> 4) & 3)) * 2 + (d >> 5)) * 64 + ((tt >> 3) & 1) * 32 + (d & 31)) * 8 + (tt & 7));
                    vo[idx] = (bf16)val;
                }
            }
        }
}

// ---------------- proj GEMM: packed A (from attn) x packed Wp -> f32 out (r19) ----------------
__global__ __launch_bounds__(256, 2) void k_gemm_proj(
    const bf16* __restrict__ Apk, const bf16* __restrict__ Bpk,
    const float* __restrict__ bias, float* __restrict__ out) {
    int orig = blockIdx.x;
    int wg = (orig & 7) * 32 + (orig >> 3);
    int row0 = (wg >> 3) * 256;
    int col0 = (wg & 7) * 128;
    int lane = threadIdx.x & 63, w = threadIdx.x >> 6;
    int wr = w >> 1, wc = w & 1;
    int lrow = lane & 15, lks = lane >> 4;

    GEMM_NOLDS_BODY84

    int trowb = row0 + wr * 128 + lks * 4;
    int tcolb = col0 + wc * 64 + lrow;
#pragma unroll
    for (int mf = 0; mf < 8; ++mf)
#pragma unroll
        for (int nf = 0; nf < 4; ++nf) {
            int cg = tcolb + nf * 16;
            float bi = bias[cg];
#pragma unroll
            for (int j2 = 0; j2 < 4; ++j2) {
                int rg = trowb + mf * 16 + j2;
                out[(size_t)rg * 1024 + cg] = acc[mf][nf][j2] + bi;
            }
        }
}

// ---------------- flash attention (causal): max-free exp2 softmax (r19) ----------------
__global__ __launch_bounds__(256, 4) void k_attn(
    const bf16* __restrict__ qp, const bf16* __restrict__ kp,
    const bf16* __restrict__ vp, bf16* __restrict__ ypk) {
    __shared__ __align__(16) bf16 Ks[2][4096];
    __shared__ __align__(16) bf16 Vs[2][4096];
    int id = blockIdx.x;
    int c = id & 255, r = id >> 8;
    int xcd = c & 7, u = c >> 3;
    int bh = xcd + 8 * (u >> 2);
    int j = (u & 3) * 4 + r;
    int bxp = (j & 1) ? 15 - (j >> 1) : (j >> 1);
    int b = bh >> 4;
    int lane = threadIdx.x & 63, w = threadIdx.x >> 6;
    int tl = lane & 31, hi = lane >> 5;
    int lane8 = lane * 8;
    const bf16* Qb = qp + (size_t)bh * 131072;
    const bf16* Kb = kp + (size_t)bh * 131072;
    const bf16* Vb = vp + (size_t)bh * 131072;

    int qt0 = bxp * 128;
    int trow0 = qt0 + w * 32;
    int t_g = trow0 + tl;

    bf16x8 qf[4];
    int qs = (trow0 >> 5) * 4;
#pragma unroll
    for (int kc = 0; kc < 4; ++kc)
        qf[kc] = *(const bf16x8*)&Qb[(qs + kc) * 512 + lane8];

    f32x16 o[2] = {};
    float l = 0.f;
    int ntb = (qt0 >> 6) + 2;
    int cur = 0;

#pragma unroll
    for (int i = 0; i < 2; ++i) {
        int u2 = 2 * w + i;
        async_load16(Kb + (size_t)u2 * 512 + lane8, &Ks[0][u2 * 512]);
        async_load16(Vb + (size_t)u2 * 512 + lane8, &Vs[0][u2 * 512]);
    }

    for (int ti = 0; ti < ntb; ++ti) {
        int s0 = ti * 64;
        if (ti + 1 < ntb) {
#pragma unroll
            for (int i = 0; i < 2; ++i) {
                int u2 = 2 * w + i;
                async_load16(Kb + (size_t)((ti + 1) * 8 + u2) * 512 + lane8, &Ks[cur ^ 1][u2 * 512]);
                async_load16(Vb + (size_t)((ti + 1) * 8 + u2) * 512 + lane8, &Vs[cur ^ 1][u2 * 512]);
            }
            asm volatile("s_waitcnt vmcnt(4)" ::: "memory");
        } else {
            asm volatile("s_waitcnt vmcnt(0)" ::: "memory");
        }
        __builtin_amdgcn_sched_barrier(0);
        __builtin_amdgcn_s_barrier();
        __builtin_amdgcn_sched_barrier(0);

        if (s0 < trow0 + 32) {
            f32x16 accs[2] = {};
            __builtin_amdgcn_s_setprio(1);
#pragma unroll
            for (int st = 0; st < 2; ++st)
#pragma unroll
                for (int kc = 0; kc < 4; ++kc) {
                    bf16x8 kf = *(const bf16x8*)&Ks[cur][(st * 4 + kc) * 512 + lane8];
                    accs[st] = MFMA32(kf, qf[kc], accs[st]);
                }
            __builtin_amdgcn_s_setprio(0);

            if (s0 + 63 > trow0) {
#pragma unroll
                for (int st = 0; st < 2; ++st)
#pragma unroll
                    for (int rr = 0; rr < 16; ++rr) {
                        int s = s0 + st * 32 + (rr & 3) + 8 * (rr >> 2) + 4 * hi;
                        if (s > t_g) accs[st][rr] = -1e30f;
                    }
            }
            float ls = 0.f;
#pragma unroll
            for (int st = 0; st < 2; ++st)
#pragma unroll
                for (int rr = 0; rr < 16; ++rr) {
                    float p = __builtin_amdgcn_exp2f(accs[st][rr]);
                    accs[st][rr] = p;
                    ls += p;
                }
            ls += __shfl_xor(ls, 32);
            l += ls;

            unsigned int pk[16];
#pragma unroll
            for (int st = 0; st < 2; ++st)
#pragma unroll
                for (int q = 0; q < 8; ++q)
                    pk[st * 8 + q] = pack2bf(accs[st][2 * q], accs[st][2 * q + 1]);
            unsigned int rv[8];
#pragma unroll
            for (int st = 0; st < 2; ++st)
#pragma unroll
                for (int i = 0; i < 4; ++i) {
                    int base = st * 8 + (i < 2 ? i : i + 2);
                    unsigned int send = hi ? pk[base] : pk[base + 2];
                    rv[st * 4 + i] = __shfl_xor(send, 32);
                }
            __builtin_amdgcn_s_setprio(1);
#pragma unroll
            for (int cc = 0; cc < 4; ++cc) {
                const int st = cc >> 1, c2 = cc & 1;
                uint32x4 pw;
                pw.x = hi ? rv[st * 4 + 2 * c2]     : pk[st * 8 + 4 * c2];
                pw.y = hi ? rv[st * 4 + 2 * c2 + 1] : pk[st * 8 + 4 * c2 + 1];
                pw.z = hi ? pk[st * 8 + 4 * c2 + 2] : rv[st * 4 + 2 * c2];
                pw.w = hi ? pk[st * 8 + 4 * c2 + 3] : rv[st * 4 + 2 * c2 + 1];
                bf16x8 pf = __builtin_bit_cast(bf16x8, pw);
#pragma unroll
                for (int dt = 0; dt < 2; ++dt) {
                    bf16x8 vf = *(const bf16x8*)&Vs[cur][(cc * 2 + dt) * 512 + lane8];
                    o[dt] = MFMA32(vf, pf, o[dt]);
                }
            }
            __builtin_amdgcn_s_setprio(0);
        }
        asm volatile("s_waitcnt lgkmcnt(0)" ::: "memory");
        __builtin_amdgcn_sched_barrier(0);
        __builtin_amdgcn_s_barrier();
        __builtin_amdgcn_sched_barrier(0);
        cur ^= 1;
    }

    int grow = b * 2048 + t_g;
    int slab = grow >> 4;
    int hkc = (bh & 15) * 2;
    float inv = 1.0f / l;
#pragma unroll
    for (int dt = 0; dt < 2; ++dt)
#pragma unroll
        for (int rq = 0; rq < 4; ++rq) {
            bf16x4v ov;
#pragma unroll
            for (int ri = 0; ri < 4; ++ri)
                ov[ri] = (bf16)(o[dt][rq * 4 + ri] * inv);
            size_t idx = (size_t)(slab * 32 + hkc + dt) * 512 + rq * 128 + (grow & 15) * 8 + 4 * hi;
            *(bf16x4v*)&ypk[idx] = ov;
        }
}

extern "C" void kernel_launch(void* const* d_in, const int* in_sizes, int n_in,
                              void* d_out, int out_size, void* d_ws, size_t ws_size,
                              hipStream_t stream) {
    const float* x = (const float*)d_in[0];
    const float* W_attn = (const float*)d_in[1];
    const float* b_attn = (const float*)d_in[2];
    const float* W_proj = (const float*)d_in[3];
    const float* b_proj = (const float*)d_in[4];
    float* out = (float*)d_out;
    float* out_mem = out + (size_t)8388608;

    char* ws = (char*)d_ws;
    bf16* xpk  = (bf16*)(ws);                        // 16MB  packed A [8192 x 1024]
    bf16* Wapk = (bf16*)(ws + ((size_t)16 << 20));   // 6MB   packed B [3072 x 1024]
    bf16* Wppk = (bf16*)(ws + ((size_t)22 << 20));   // 2MB   packed B [1024 x 1024]
    bf16* q    = (bf16*)(ws + ((size_t)24 << 20));   // 16MB  attn-packed frags
    bf16* k    = (bf16*)(ws + ((size_t)40 << 20));   // 16MB  attn-packed frags
    bf16* vT   = (bf16*)(ws + ((size_t)56 << 20));   // 16MB  attn-packed frags
    bf16* ypk  = (bf16*)(ws + ((size_t)72 << 20));   // 16MB  packed A [8192 x 1024]

    k_pre<<<3072, 256, 0, stream>>>(x, W_attn, W_proj, xpk, out_mem, Wapk, Wppk);
    k_gemm_qkv<<<384, 512, 0, stream>>>(xpk, Wapk, b_attn, q, k, vT);
    k_attn<<<1024, 256, 0, stream>>>(q, k, vT, ypk);
    k_gemm_proj<<<256, 256, 0, stream>>>(ypk, Wppk, b_proj, out);
}

// Round 21
// 152.304 us; speedup vs baseline: 1.1278x; 1.1278x over previous
//
#include <hip/hip_runtime.h>
#include <hip/hip_bf16.h>

typedef __bf16 bf16;
typedef __bf16 bf16x8 __attribute__((ext_vector_type(8)));
typedef __bf16 bf16x4v __attribute__((ext_vector_type(4)));
typedef float f32x4 __attribute__((ext_vector_type(4)));
typedef float f32x16 __attribute__((ext_vector_type(16)));
typedef float float4v __attribute__((ext_vector_type(4)));
typedef unsigned int uint32x4 __attribute__((ext_vector_type(4)));

#define MFMA16(a, b, c) __builtin_amdgcn_mfma_f32_16x16x32_bf16(a, b, c, 0, 0, 0)
#define MFMA32(a, b, c) __builtin_amdgcn_mfma_f32_32x32x16_bf16(a, b, c, 0, 0, 0)

// q pre-scale: 1/sqrt(64) * log2(e)  (softmax runs in exp2 domain)
#define SCALE_Q 0.1803368801111f

__device__ __forceinline__ void async_load16(const bf16* g, bf16* l) {
    __builtin_amdgcn_global_load_lds(
        (const __attribute__((address_space(1))) void*)g,
        (__attribute__((address_space(3))) void*)l,
        16, 0, 0);
}

__device__ __forceinline__ unsigned int pack2bf(float a, float b) {
    bf16 x = (bf16)a, y = (bf16)b;
    unsigned short ux = __builtin_bit_cast(unsigned short, x);
    unsigned short uy = __builtin_bit_cast(unsigned short, y);
    return (unsigned int)ux | ((unsigned int)uy << 16);
}

// =================== fragment-packed layout ===================
// Element (row t, k) of a [T][K] bf16 matrix (K=1024) lives at:
//   line = (t>>4)*32 + (k>>5);  lane = (t&15) + 16*((k>>3)&3);  j = k&7
//   idx  = line*512 + lane*8 + j
// One MFMA A/B fragment (16 rows x 32 k) = one 1KB line = base + lane*16B.

// ---------------- k_pre: LDS-tiled packer (coalesced load + store) ----------------
__global__ __launch_bounds__(256) void k_pre(
    const float* __restrict__ x, const float* __restrict__ W_attn,
    const float* __restrict__ W_proj,
    bf16* __restrict__ xpk, float* __restrict__ out_mem,
    bf16* __restrict__ Wapk, bf16* __restrict__ Wppk) {
    __shared__ float tile[64][65];
    int bid = blockIdx.x, tid = threadIdx.x;

    if (bid < 2048) {
        // ---- x tile: rows t0..t0+63, cols k0..k0+63 ----
        int bt = bid >> 4, bk = bid & 15;
        int t0 = bt * 64, k0 = bk * 64;
#pragma unroll
        for (int i = 0; i < 4; ++i) {
            int idx = tid + 256 * i;
            int r = idx >> 4, c4 = (idx & 15) * 4;
            float4v v = *(const float4v*)(x + (size_t)(t0 + r) * 1024 + k0 + c4);
            *(float4v*)&tile[r][c4] = v;
            int tb = (t0 + r) & 2047;
            if (tb >= 1536) {
                int b = (t0 + r) >> 11;
                *(float4v*)(out_mem + ((size_t)(b * 512 + (tb - 1536))) * 1024 + k0 + c4) = v;
            }
        }
        __syncthreads();
#pragma unroll
        for (int i = 0; i < 2; ++i) {
            int idx = tid + 256 * i;
            int lineL = idx >> 6, lane = idx & 63;
            int slab_l = lineL >> 1, kc_l = lineL & 1;
            int tl = slab_l * 16 + (lane & 15);
            int kl = kc_l * 32 + (lane >> 4) * 8;
            bf16x8 o;
#pragma unroll
            for (int j = 0; j < 8; ++j)
                o[j] = (bf16)tile[tl][kl + j];
            size_t line_g = (size_t)(bt * 4 + slab_l) * 32 + (bk * 2 + kc_l);
            *(bf16x8*)(xpk + line_g * 512 + lane * 8) = o;
        }
    } else {
        // ---- W tile: k-rows kt*64.., n-cols nt*64.. ----
        const float* W;  bf16* WT;  int C, kt, nt;
        if (bid < 2816) {
            int b2 = bid - 2048;
            W = W_attn; WT = Wapk; C = 3072; kt = b2 & 15; nt = b2 >> 4;
        } else {
            int b3 = bid - 2816;
            W = W_proj; WT = Wppk; C = 1024; kt = b3 & 15; nt = b3 >> 4;
        }
        int k0 = kt * 64, n0 = nt * 64;
#pragma unroll
        for (int i = 0; i < 4; ++i) {
            int idx = tid + 256 * i;
            int r = idx >> 4, c4 = (idx & 15) * 4;
            *(float4v*)&tile[r][c4] = *(const float4v*)(W + (size_t)(k0 + r) * C + n0 + c4);
        }
        __syncthreads();
#pragma unroll
        for (int i = 0; i < 2; ++i) {
            int idx = tid + 256 * i;
            int lineL = idx >> 6, lane = idx & 63;
            int slab_l = lineL >> 1, kc_l = lineL & 1;
            int nl = slab_l * 16 + (lane & 15);
            int kl = kc_l * 32 + (lane >> 4) * 8;
            bf16x8 o;
#pragma unroll
            for (int j = 0; j < 8; ++j)
                o[j] = (bf16)tile[kl + j][nl];
            size_t line_g = (size_t)(nt * 4 + slab_l) * 32 + (kt * 2 + kc_l);
            *(bf16x8*)(WT + line_g * 512 + lane * 8) = o;
        }
    }
}

// ============ LDS-free GEMM body: per-wave 128x64 (8x4 frags) ============
#define GEMM_NOLDS_BODY84                                                                \
    const bf16* Abase = Apk + (size_t)(((row0 >> 4) + wr * 8) * 32) * 512 + lane * 8;    \
    const bf16* Bbase = Bpk + (size_t)(((col0 >> 4) + wc * 4) * 32) * 512 + lane * 8;    \
    f32x4 acc[8][4] = {};                                                                \
    bf16x8 a0[8], b0[4], a1[8], b1[4];                                                   \
    _Pragma("unroll")                                                                    \
    for (int m = 0; m < 8; ++m) a0[m] = *(const bf16x8*)(Abase + m * 16384);             \
    _Pragma("unroll")                                                                    \
    for (int n = 0; n < 4; ++n) b0[n] = *(const bf16x8*)(Bbase + n * 16384);             \
    for (int t = 0; t < 16; ++t) {                                                       \
        int o1 = (2 * t + 1) * 512;                                                      \
        _Pragma("unroll")                                                                \
        for (int m = 0; m < 8; ++m) a1[m] = *(const bf16x8*)(Abase + m * 16384 + o1);    \
        _Pragma("unroll")                                                                \
        for (int n = 0; n < 4; ++n) b1[n] = *(const bf16x8*)(Bbase + n * 16384 + o1);    \
        __builtin_amdgcn_s_setprio(1);                                                   \
        _Pragma("unroll")                                                                \
        for (int m = 0; m < 8; ++m)                                                      \
            _Pragma("unroll")                                                            \
            for (int n = 0; n < 4; ++n)                                                  \
                acc[m][n] = MFMA16(a0[m], b0[n], acc[m][n]);                             \
        __builtin_amdgcn_s_setprio(0);                                                   \
        if (t < 15) {                                                                    \
            int o2 = (2 * t + 2) * 512;                                                  \
            _Pragma("unroll")                                                            \
            for (int m = 0; m < 8; ++m) a0[m] = *(const bf16x8*)(Abase + m * 16384 + o2);\
            _Pragma("unroll")                                                            \
            for (int n = 0; n < 4; ++n) b0[n] = *(const bf16x8*)(Bbase + n * 16384 + o2);\
        }                                                                                \
        __builtin_amdgcn_s_setprio(1);                                                   \
        _Pragma("unroll")                                                                \
        for (int m = 0; m < 8; ++m)                                                      \
            _Pragma("unroll")                                                            \
            for (int n = 0; n < 4; ++n)                                                  \
                acc[m][n] = MFMA16(a1[m], b1[n], acc[m][n]);                             \
        __builtin_amdgcn_s_setprio(0);                                                   \
    }

// ---------------- QKV GEMM (r19): 256 thr, 256x128 block, col-outer/row-inner XCD ----------------
__global__ __launch_bounds__(256, 2) void k_gemm_qkv(
    const bf16* __restrict__ Apk, const bf16* __restrict__ Bpk,
    const float* __restrict__ bias,
    bf16* __restrict__ qo, bf16* __restrict__ ko, bf16* __restrict__ vo) {
    int orig = blockIdx.x;
    int xcd = orig & 7, j = orig >> 3;           // j in [0,96)
    int col0 = (j >> 2) * 128;                   // 24 col panels, outer
    int row0 = (xcd * 4 + (j & 3)) * 256;        // 32 row panels, 4/XCD, inner
    int lane = threadIdx.x & 63, w = threadIdx.x >> 6;
    int wr = w >> 1, wc = w & 1;
    int lrow = lane & 15, lks = lane >> 4;

    GEMM_NOLDS_BODY84

    int trowb = row0 + wr * 128 + lks * 4;
    int tcolb = col0 + wc * 64 + lrow;
#pragma unroll
    for (int mf = 0; mf < 8; ++mf)
#pragma unroll
        for (int nf = 0; nf < 4; ++nf) {
            int cg = tcolb + nf * 16;
            float bi = bias[cg];
#pragma unroll
            for (int j2 = 0; j2 < 4; ++j2) {
                int rg = trowb + mf * 16 + j2;
                float val = acc[mf][nf][j2] + bi;
                int b = rg >> 11, tt = rg & 2047;
                if (cg < 1024) {
                    int h = cg >> 6, d = cg & 63;
                    size_t base = (size_t)(b * 16 + h) * 131072;
                    size_t idx = base + (size_t)((((tt >> 5) * 4 + (d >> 4)) * 64 + ((d >> 3) & 1) * 32 + (tt & 31)) * 8 + (d & 7));
                    qo[idx] = (bf16)(val * SCALE_Q);
                } else if (cg < 2048) {
                    int c2 = cg - 1024;
                    int h = c2 >> 6, d = c2 & 63;
                    size_t base = (size_t)(b * 16 + h) * 131072;
                    size_t idx = base + (size_t)((((tt >> 5) * 4 + (d >> 4)) * 64 + ((d >> 3) & 1) * 32 + (tt & 31)) * 8 + (d & 7));
                    ko[idx] = (bf16)val;
                } else {
                    int c2 = cg - 2048;
                    int h = c2 >> 6, d = c2 & 63;
                    size_t base = (size_t)(b * 16 + h) * 131072;
                    size_t idx = base + (size_t)(((((tt >> 6) * 4 + ((tt >> 4) & 3)) * 2 + (d >> 5)) * 64 + ((tt >> 3) & 1) * 32 + (d & 31)) * 8 + (tt & 7));
                    vo[idx] = (bf16)val;
                }
            }
        }
}

// ---------------- proj GEMM: packed A (from attn) x packed Wp -> f32 out (r19) ----------------
__global__ __launch_bounds__(256, 2) void k_gemm_proj(
    const bf16* __restrict__ Apk, const bf16* __restrict__ Bpk,
    const float* __restrict__ bias, float* __restrict__ out) {
    int orig = blockIdx.x;
    int wg = (orig & 7) * 32 + (orig >> 3);
    int row0 = (wg >> 3) * 256;
    int col0 = (wg & 7) * 128;
    int lane = threadIdx.x & 63, w = threadIdx.x >> 6;
    int wr = w >> 1, wc = w & 1;
    int lrow = lane & 15, lks = lane >> 4;

    GEMM_NOLDS_BODY84

    int trowb = row0 + wr * 128 + lks * 4;
    int tcolb = col0 + wc * 64 + lrow;
#pragma unroll
    for (int mf = 0; mf < 8; ++mf)
#pragma unroll
        for (int nf = 0; nf < 4; ++nf) {
            int cg = tcolb + nf * 16;
            float bi = bias[cg];
#pragma unroll
            for (int j2 = 0; j2 < 4; ++j2) {
                int rg = trowb + mf * 16 + j2;
                out[(size_t)rg * 1024 + cg] = acc[mf][nf][j2] + bi;
            }
        }
}

// ---------------- flash attention (causal): max-free exp2 softmax (r19) ----------------
__global__ __launch_bounds__(256, 4) void k_attn(
    const bf16* __restrict__ qp, const bf16* __restrict__ kp,
    const bf16* __restrict__ vp, bf16* __restrict__ ypk) {
    __shared__ __align__(16) bf16 Ks[2][4096];
    __shared__ __align__(16) bf16 Vs[2][4096];
    int id = blockIdx.x;
    int c = id & 255, r = id >> 8;
    int xcd = c & 7, u = c >> 3;
    int bh = xcd + 8 * (u >> 2);
    int j = (u & 3) * 4 + r;
    int bxp = (j & 1) ? 15 - (j >> 1) : (j >> 1);
    int b = bh >> 4;
    int lane = threadIdx.x & 63, w = threadIdx.x >> 6;
    int tl = lane & 31, hi = lane >> 5;
    int lane8 = lane * 8;
    const bf16* Qb = qp + (size_t)bh * 131072;
    const bf16* Kb = kp + (size_t)bh * 131072;
    const bf16* Vb = vp + (size_t)bh * 131072;

    int qt0 = bxp * 128;
    int trow0 = qt0 + w * 32;
    int t_g = trow0 + tl;

    bf16x8 qf[4];
    int qs = (trow0 >> 5) * 4;
#pragma unroll
    for (int kc = 0; kc < 4; ++kc)
        qf[kc] = *(const bf16x8*)&Qb[(qs + kc) * 512 + lane8];

    f32x16 o[2] = {};
    float l = 0.f;
    int ntb = (qt0 >> 6) + 2;
    int cur = 0;

#pragma unroll
    for (int i = 0; i < 2; ++i) {
        int u2 = 2 * w + i;
        async_load16(Kb + (size_t)u2 * 512 + lane8, &Ks[0][u2 * 512]);
        async_load16(Vb + (size_t)u2 * 512 + lane8, &Vs[0][u2 * 512]);
    }

    for (int ti = 0; ti < ntb; ++ti) {
        int s0 = ti * 64;
        if (ti + 1 < ntb) {
#pragma unroll
            for (int i = 0; i < 2; ++i) {
                int u2 = 2 * w + i;
                async_load16(Kb + (size_t)((ti + 1) * 8 + u2) * 512 + lane8, &Ks[cur ^ 1][u2 * 512]);
                async_load16(Vb + (size_t)((ti + 1) * 8 + u2) * 512 + lane8, &Vs[cur ^ 1][u2 * 512]);
            }
            asm volatile("s_waitcnt vmcnt(4)" ::: "memory");
        } else {
            asm volatile("s_waitcnt vmcnt(0)" ::: "memory");
        }
        __builtin_amdgcn_sched_barrier(0);
        __builtin_amdgcn_s_barrier();
        __builtin_amdgcn_sched_barrier(0);

        if (s0 < trow0 + 32) {
            f32x16 accs[2] = {};
            __builtin_amdgcn_s_setprio(1);
#pragma unroll
            for (int st = 0; st < 2; ++st)
#pragma unroll
                for (int kc = 0; kc < 4; ++kc) {
                    bf16x8 kf = *(const bf16x8*)&Ks[cur][(st * 4 + kc) * 512 + lane8];
                    accs[st] = MFMA32(kf, qf[kc], accs[st]);
                }
            __builtin_amdgcn_s_setprio(0);

            if (s0 + 63 > trow0) {
#pragma unroll
                for (int st = 0; st < 2; ++st)
#pragma unroll
                    for (int rr = 0; rr < 16; ++rr) {
                        int s = s0 + st * 32 + (rr & 3) + 8 * (rr >> 2) + 4 * hi;
                        if (s > t_g) accs[st][rr] = -1e30f;
                    }
            }
            float ls = 0.f;
#pragma unroll
            for (int st = 0; st < 2; ++st)
#pragma unroll
                for (int rr = 0; rr < 16; ++rr) {
                    float p = __builtin_amdgcn_exp2f(accs[st][rr]);
                    accs[st][rr] = p;
                    ls += p;
                }
            ls += __shfl_xor(ls, 32);
            l += ls;

            unsigned int pk[16];
#pragma unroll
            for (int st = 0; st < 2; ++st)
#pragma unroll
                for (int q = 0; q < 8; ++q)
                    pk[st * 8 + q] = pack2bf(accs[st][2 * q], accs[st][2 * q + 1]);
            unsigned int rv[8];
#pragma unroll
            for (int st = 0; st < 2; ++st)
#pragma unroll
                for (int i = 0; i < 4; ++i) {
                    int base = st * 8 + (i < 2 ? i : i + 2);
                    unsigned int send = hi ? pk[base] : pk[base + 2];
                    rv[st * 4 + i] = __shfl_xor(send, 32);
                }
            __builtin_amdgcn_s_setprio(1);
#pragma unroll
            for (int cc = 0; cc < 4; ++cc) {
                const int st = cc >> 1, c2 = cc & 1;
                uint32x4 pw;
                pw.x = hi ? rv[st * 4 + 2 * c2]     : pk[st * 8 + 4 * c2];
                pw.y = hi ? rv[st * 4 + 2 * c2 + 1] : pk[st * 8 + 4 * c2 + 1];
                pw.z = hi ? pk[st * 8 + 4 * c2 + 2] : rv[st * 4 + 2 * c2];
                pw.w = hi ? pk[st * 8 + 4 * c2 + 3] : rv[st * 4 + 2 * c2 + 1];
                bf16x8 pf = __builtin_bit_cast(bf16x8, pw);
#pragma unroll
                for (int dt = 0; dt < 2; ++dt) {
                    bf16x8 vf = *(const bf16x8*)&Vs[cur][(cc * 2 + dt) * 512 + lane8];
                    o[dt] = MFMA32(vf, pf, o[dt]);
                }
            }
            __builtin_amdgcn_s_setprio(0);
        }
        asm volatile("s_waitcnt lgkmcnt(0)" ::: "memory");
        __builtin_amdgcn_sched_barrier(0);
        __builtin_amdgcn_s_barrier();
        __builtin_amdgcn_sched_barrier(0);
        cur ^= 1;
    }

    int grow = b * 2048 + t_g;
    int slab = grow >> 4;
    int hkc = (bh & 15) * 2;
    float inv = 1.0f / l;
#pragma unroll
    for (int dt = 0; dt < 2; ++dt)
#pragma unroll
        for (int rq = 0; rq < 4; ++rq) {
            bf16x4v ov;
#pragma unroll
            for (int ri = 0; ri < 4; ++ri)
                ov[ri] = (bf16)(o[dt][rq * 4 + ri] * inv);
            size_t idx = (size_t)(slab * 32 + hkc + dt) * 512 + rq * 128 + (grow & 15) * 8 + 4 * hi;
            *(bf16x4v*)&ypk[idx] = ov;
        }
}

extern "C" void kernel_launch(void* const* d_in, const int* in_sizes, int n_in,
                              void* d_out, int out_size, void* d_ws, size_t ws_size,
                              hipStream_t stream) {
    const float* x = (const float*)d_in[0];
    const float* W_attn = (const float*)d_in[1];
    const float* b_attn = (const float*)d_in[2];
    const float* W_proj = (const float*)d_in[3];
    const float* b_proj = (const float*)d_in[4];
    float* out = (float*)d_out;
    float* out_mem = out + (size_t)8388608;

    char* ws = (char*)d_ws;
    bf16* xpk  = (bf16*)(ws);                        // 16MB  packed A [8192 x 1024]
    bf16* Wapk = (bf16*)(ws + ((size_t)16 << 20));   // 6MB   packed B [3072 x 1024]
    bf16* Wppk = (bf16*)(ws + ((size_t)22 << 20));   // 2MB   packed B [1024 x 1024]
    bf16* q    = (bf16*)(ws + ((size_t)24 << 20));   // 16MB  attn-packed frags
    bf16* k    = (bf16*)(ws + ((size_t)40 << 20));   // 16MB  attn-packed frags
    bf16* vT   = (bf16*)(ws + ((size_t)56 << 20));   // 16MB  attn-packed frags
    bf16* ypk  = (bf16*)(ws + ((size_t)72 << 20));   // 16MB  packed A [8192 x 1024]

    k_pre<<<3072, 256, 0, stream>>>(x, W_attn, W_proj, xpk, out_mem, Wapk, Wppk);
    k_gemm_qkv<<<768, 256, 0, stream>>>(xpk, Wapk, b_attn, q, k, vT);
    k_attn<<<1024, 256, 0, stream>>>(q, k, vT, ypk);
    k_gemm_proj<<<256, 256, 0, stream>>>(ypk, Wppk, b_proj, out);
}